// Round 9
// baseline (271.319 us; speedup 1.0000x reference)
//
#include <hip/hip_runtime.h>
#include <stdint.h>

typedef _Float16 f16;
typedef _Float16 half8 __attribute__((ext_vector_type(8)));
typedef _Float16 half4v __attribute__((ext_vector_type(4)));
typedef float f32x4 __attribute__((ext_vector_type(4)));

#define DEV static __device__ __forceinline__

DEV f32x4 mfma16(half8 a, half8 b, f32x4 c) {
  return __builtin_amdgcn_mfma_f32_16x16x32_f16(a, b, c, 0, 0, 0);
}

// async global->LDS 16B: LDS dst is wave-uniform base + lane*16
DEV void cp16(const f16* g, f16* l) {
  __builtin_amdgcn_global_load_lds(
      (const __attribute__((address_space(1))) void*)g,
      (__attribute__((address_space(3))) void*)l, 16, 0, 0);
}

// Problem constants: B=2, S=2048, DIM=1024, H=16, D=64, B1=B2=8, F=32, ITERS=2
// seq position s = g*64 + i*8 + j ; kv position = f*64 + k*8 + l
// Packed slices: slice(bh,g,f) base = (bh*528 + g(g+1)/2 + f) * 512 elems.
// L slice layout: o = j*64 + k*8 + i (f16 logits)
// R slice layout: o = k*64 + j*8 + l (f16 probs)
// Pg slice layout: o = j*64 + k*8 + ii, f16, stored ii=ih*4+mt holds true
//   i = mt*2+ih  (k_out lane (jl,ih) loads 8B of exactly its 4 values)
// vth layout: [bh][f][d][64] f16.

// ---------------- K1: cast x, wq|wk|wv -> fp16 ----------------
__global__ __launch_bounds__(256) void k_cast(
    const float* __restrict__ x, const float* __restrict__ wq,
    const float* __restrict__ wk, const float* __restrict__ wv,
    f16* __restrict__ xh, f16* __restrict__ wcat) {
  const int64_t nx4 = 4194304 / 4;
  const int64_t nw4 = 1048576 / 4;
  int64_t stride = (int64_t)gridDim.x * blockDim.x;
  for (int64_t i = (int64_t)blockIdx.x * blockDim.x + threadIdx.x;
       i < nx4 + 3 * nw4; i += stride) {
    const float* src; f16* dst; int64_t off;
    if (i < nx4) { src = x; dst = xh; off = i; }
    else {
      int64_t r = i - nx4;
      int ws_ = (int)(r / nw4);
      off = r - (int64_t)ws_ * nw4;
      src = (ws_ == 0) ? wq : ((ws_ == 1) ? wk : wv);
      dst = wcat + (int64_t)ws_ * 1048576;
    }
    float4 v = ((const float4*)src)[off];
    half4v hh; hh[0] = (f16)v.x; hh[1] = (f16)v.y; hh[2] = (f16)v.z; hh[3] = (f16)v.w;
    ((half4v*)dst)[off] = hh;
  }
}

// ---------------- K2: P = xh @ wcat^T, async-staged, XOR-swizzled LDS -------
__global__ __launch_bounds__(256) void k_gemm(
    const f16* __restrict__ A, const f16* __restrict__ Bm,
    float* __restrict__ P) {
  __shared__ f16 As[128 * 64];   // 16 KB, unpadded, swizzled
  __shared__ f16 Bs[128 * 64];
  const int t = threadIdx.x;
  const int wave = t >> 6, lane = t & 63, quad = lane >> 4, ln = lane & 15;
  const int tM = blockIdx.x / 24, tN = blockIdx.x % 24;
  const int wm = wave >> 1, wn = wave & 1;
  f32x4 acc[4][4];
#pragma unroll
  for (int a = 0; a < 4; ++a)
#pragma unroll
    for (int b = 0; b < 4; ++b) { f32x4 z = {0.f, 0.f, 0.f, 0.f}; acc[a][b] = z; }
  const int srow = t >> 3;
  const int c = (t & 7) ^ (srow & 7);
  const f16* Ag = A + (int64_t)(tM * 128 + srow) * 1024 + c * 8;
  const f16* Bg = Bm + (int64_t)(tN * 128 + srow) * 1024 + c * 8;
  for (int kt = 0; kt < 16; ++kt) {
    __syncthreads();
#pragma unroll
    for (int it = 0; it < 4; ++it) {
      cp16(Ag + (int64_t)it * 32 * 1024 + kt * 64, &As[it * 2048 + wave * 512]);
      cp16(Bg + (int64_t)it * 32 * 1024 + kt * 64, &Bs[it * 2048 + wave * 512]);
    }
    __syncthreads();
#pragma unroll
    for (int ks = 0; ks < 2; ++ks) {
      const int cs = ((ks * 4 + quad) ^ (ln & 7)) * 8;
      half8 bf[4];
#pragma unroll
      for (int tn = 0; tn < 4; ++tn)
        bf[tn] = *(const half8*)&Bs[(wn * 64 + tn * 16 + ln) * 64 + cs];
#pragma unroll
      for (int tm = 0; tm < 4; ++tm) {
        half8 af = *(const half8*)&As[(wm * 64 + tm * 16 + ln) * 64 + cs];
#pragma unroll
        for (int tn = 0; tn < 4; ++tn)
          acc[tm][tn] = mfma16(af, bf[tn], acc[tm][tn]);
      }
    }
  }
#pragma unroll
  for (int tm = 0; tm < 4; ++tm)
#pragma unroll
    for (int tn = 0; tn < 4; ++tn)
#pragma unroll
      for (int r2 = 0; r2 < 4; ++r2) {
        int row = tM * 128 + wm * 64 + tm * 16 + quad * 4 + r2;
        int col = tN * 128 + wn * 64 + tn * 16 + ln;
        P[(int64_t)row * 3072 + col] = acc[tm][tn][r2];
      }
}

// ---------------- K3: rmsnorm+rope+scale for q,k; v -> [bh][f][d][64] f16 ---
__global__ __launch_bounds__(256) void k_epilogue(
    const float* __restrict__ P, const float* __restrict__ cosg,
    const float* __restrict__ sing, const float* __restrict__ gq,
    const float* __restrict__ gk, f16* __restrict__ qh,
    f16* __restrict__ kh, f16* __restrict__ vth) {
  __shared__ f16 vbuf[64 * 72];
  const int t = threadIdx.x;
  const int bid = blockIdx.x;
  const int st = bid & 31, h = (bid >> 5) & 15, b = bid >> 9;
  const int r = t >> 2, qt = t & 3, c0 = qt * 16;
  const int s = st * 64 + r;
  const int64_t rowbase = (int64_t)(b * 2048 + s) * 3072;
  const float scale = 0.35355339059327373f;  // 64^-0.25
#pragma unroll
  for (int m = 0; m < 2; ++m) {
    const float* gv = (m == 0) ? gq : gk;
    const int colbase = m * 1024 + h * 64 + c0;
    float xv[16];
#pragma unroll
    for (int c = 0; c < 4; ++c) {
      float4 v4 = *(const float4*)&P[rowbase + colbase + c * 4];
      xv[c * 4 + 0] = v4.x; xv[c * 4 + 1] = v4.y;
      xv[c * 4 + 2] = v4.z; xv[c * 4 + 3] = v4.w;
    }
    float ss = 0.f;
#pragma unroll
    for (int c = 0; c < 16; ++c) ss += xv[c] * xv[c];
    ss += __shfl_xor(ss, 1, 64);
    ss += __shfl_xor(ss, 2, 64);
    float rs = rsqrtf(ss * (1.f / 64.f) + 1e-6f);
    alignas(16) f16 res[16];
#pragma unroll
    for (int ci = 0; ci < 16; ci += 2) {
      int d0 = c0 + ci, d1 = d0 + 1;
      float av = xv[ci] * rs * gv[d0];
      float bv = xv[ci + 1] * rs * gv[d1];
      float c0v = cosg[s * 64 + d0], c1v = cosg[s * 64 + d1];
      float s0v = sing[s * 64 + d0], s1v = sing[s * 64 + d1];
      res[ci]     = (f16)((av * c0v - bv * s0v) * scale);
      res[ci + 1] = (f16)((bv * c1v + av * s1v) * scale);
    }
    f16* dst = ((m == 0) ? qh : kh) + (int64_t)((b * 16 + h) * 2048 + s) * 64 + c0;
    *(half8*)dst = *(const half8*)&res[0];
    *(half8*)(dst + 8) = *(const half8*)&res[8];
  }
  {
    const int colbase = 2048 + h * 64 + c0;
#pragma unroll
    for (int c = 0; c < 4; ++c) {
      float4 v4 = *(const float4*)&P[rowbase + colbase + c * 4];
      vbuf[(c0 + c * 4 + 0) * 72 + r] = (f16)v4.x;
      vbuf[(c0 + c * 4 + 1) * 72 + r] = (f16)v4.y;
      vbuf[(c0 + c * 4 + 2) * 72 + r] = (f16)v4.z;
      vbuf[(c0 + c * 4 + 3) * 72 + r] = (f16)v4.w;
    }
    __syncthreads();
    const int d = t >> 2, sc = qt * 16;
    alignas(16) f16 tmp[16];
#pragma unroll
    for (int ci = 0; ci < 16; ++ci) tmp[ci] = vbuf[d * 72 + sc + ci];
    f16* dst = vth + (int64_t)(((b * 16 + h) * 32 + st) * 64 + d) * 64 + sc;
    *(half8*)dst = *(const half8*)&tmp[0];
    *(half8*)(dst + 8) = *(const half8*)&tmp[8];
  }
}

// ---------------- K4: phase kernel — 4 units/block (1 per wave) -------------
// Unit u = blockIdx.x*4 + wave  ->  (bh = u/528, rem = u%528 -> (g,f)).
// Each wave owns a private 9.3 KB Sw region; 37.4 KB/block -> 4 blocks/CU
// = 16 waves/CU (beats the ~8 single-wave-WG residency cap seen in R8).
// Sw layout (f16 index): i*584 + j*72 + k*8 + l.
__global__ __launch_bounds__(256) void k_phase(
    const f16* __restrict__ qh, const f16* __restrict__ kh,
    f16* __restrict__ Lg, f16* __restrict__ Rg,
    const f16* __restrict__ Pg, int iter) {
  __shared__ f16 SwAll[4][8 * 584];   // 37376 B
  const int t = threadIdx.x;
  const int wave = t >> 6, lane = t & 63;
  const int quad = lane >> 4, ln = lane & 15;
  const int jr = lane >> 3, kr = lane & 7;   // lane = jr*8 + kr
  f16* Sw = &SwAll[wave][0];

  const int unit = blockIdx.x * 4 + wave;
  const int bh = unit / 528;
  const int rem = unit - bh * 528;
  int g = (int)((sqrtf(8.f * (float)rem + 1.f) - 1.f) * 0.5f);
  while ((g + 1) * (g + 2) / 2 <= rem) ++g;
  while (g * (g + 1) / 2 > rem) --g;
  const int f = rem - g * (g + 1) / 2;

  const f16* qg = qh + (int64_t)(bh * 2048 + g * 64) * 64;
  const f16* kf = kh + (int64_t)(bh * 2048 + f * 64) * 64;
  const int64_t sbase = ((int64_t)bh * 528 + ((g * (g + 1)) >> 1) + f) * 512;
  f16* Lp = Lg + sbase;

  half8 afr[2][4], bfr[2][4];
#pragma unroll
  for (int ks = 0; ks < 2; ++ks)
#pragma unroll
    for (int t4 = 0; t4 < 4; ++t4) {
      afr[ks][t4] = *(const half8*)&qg[(t4 * 16 + ln) * 64 + ks * 32 + quad * 8];
      bfr[ks][t4] = *(const half8*)&kf[(t4 * 16 + ln) * 64 + ks * 32 + quad * 8];
    }
  float p[8], cR = 0.f;
  if (iter) {  // this lane's L-probs (precomputed f16, permuted layout)
    half8 ph = *(const half8*)&Pg[sbase + lane * 8];
    p[0] = (float)ph[0]; p[2] = (float)ph[1]; p[4] = (float)ph[2]; p[6] = (float)ph[3];
    p[1] = (float)ph[4]; p[3] = (float)ph[5]; p[5] = (float)ph[6]; p[7] = (float)ph[7];
#pragma unroll
    for (int i = 0; i < 8; ++i) cR += p[i];
  }
  f32x4 acc[4][4];
#pragma unroll
  for (int a = 0; a < 4; ++a)
#pragma unroll
    for (int b = 0; b < 4; ++b) { f32x4 z = {0.f, 0.f, 0.f, 0.f}; acc[a][b] = z; }
#pragma unroll
  for (int ks = 0; ks < 2; ++ks)
#pragma unroll
    for (int mt = 0; mt < 4; ++mt)
#pragma unroll
      for (int nt = 0; nt < 4; ++nt)
        acc[mt][nt] = mfma16(afr[ks][mt], bfr[ks][nt], acc[mt][nt]);
  // scatter store C-layout -> f16 Sw: m=(i,j) rows, n=(k,l) cols
#pragma unroll
  for (int nt = 0; nt < 4; ++nt) {
    const int n = nt * 16 + ln;
    const int cp = (n >> 3) * 8 + (n & 7);
#pragma unroll
    for (int mt = 0; mt < 4; ++mt)
#pragma unroll
      for (int r2 = 0; r2 < 4; ++r2) {
        const int m = mt * 16 + quad * 4 + r2;
        Sw[(m >> 3) * 584 + (m & 7) * 72 + cp] = (f16)acc[mt][nt][r2];
      }
  }
  __syncthreads();   // 4 symmetric waves: minimal skew
  const int rb = jr * 72 + kr * 8;
  float va[8];
  if (!iter) {
    // L = block identity: bR[l] = S[(kr,jr)][(kr,l)], cR = 1
    half8 s8 = *(const half8*)&Sw[kr * 584 + rb];
    const float sc = 1.f / (1.f + 1e-6f);
#pragma unroll
    for (int l = 0; l < 8; ++l) va[l] = (float)s8[l] * sc;
  } else {
    float bR[8];
#pragma unroll
    for (int l = 0; l < 8; ++l) bR[l] = 0.f;
#pragma unroll
    for (int i = 0; i < 8; ++i) {
      half8 s8 = *(const half8*)&Sw[i * 584 + rb];
#pragma unroll
      for (int l = 0; l < 8; ++l) bR[l] += p[i] * (float)s8[l];
    }
    const float rc = 1.f / (cR + 1e-6f);
#pragma unroll
    for (int l = 0; l < 8; ++l) va[l] = bR[l] * rc;
  }
  float mx = va[0];
#pragma unroll
  for (int l = 1; l < 8; ++l) mx = fmaxf(mx, va[l]);
  float ex[8], sm = 0.f;
#pragma unroll
  for (int l = 0; l < 8; ++l) { ex[l] = __expf(va[l] - mx); sm += ex[l]; }
  const float inv = 1.f / sm;
  float rr[8], rl = 0.f;
#pragma unroll
  for (int l = 0; l < 8; ++l) {
    rr[l] = ex[l] * inv;
    rl += rr[l] * __logf(fmaxf(rr[l], 1e-30f));
  }
  if (iter) {
    half8 r8;
#pragma unroll
    for (int l = 0; l < 8; ++l) r8[l] = (f16)rr[l];
    *(half8*)&Rg[sbase + kr * 64 + jr * 8] = r8;
  }
  // bL[i] = sum_l rr*S[i] - rl ; rows re-read from LDS (prefetchable)
  half8 blh;
#pragma unroll
  for (int i = 0; i < 8; ++i) {
    half8 s8 = *(const half8*)&Sw[i * 584 + rb];
    float s = 0.f;
#pragma unroll
    for (int l = 0; l < 8; ++l) s += rr[l] * (float)s8[l];
    blh[i] = (f16)(s - rl);
  }
  *(half8*)&Lp[lane * 8] = blh;
}

// ---------------- K5: joint softmax -> f16 probs Pg (permuted layout) -------
__global__ __launch_bounds__(256) void k_probs(
    const f16* __restrict__ Lg, f16* __restrict__ Pg) {
  __shared__ f16 Ls[32 * 584];   // 37,376 B ; layout f*584 + j*72 + k*8 + i
  __shared__ float stt[128];     // [j*8+i]{mx, 1/sum}
  const int t = threadIdx.x;
  const int g = 31 - (blockIdx.x & 31), bh = blockIdx.x >> 5;
  const int64_t sb = ((int64_t)bh * 528 + ((g * (g + 1)) >> 1)) * 512;
  const f16* Lp = Lg + sb;
  for (int f = 0; f <= g; ++f) {
    const int o = 2 * t;
    *(uint32_t*)&Ls[f * 584 + (o >> 6) * 72 + (o & 63)] =
        *(const uint32_t*)&Lp[f * 512 + o];
  }
  __syncthreads();
  {
    const int p = t >> 2, sub = t & 3;
    const int base = (p >> 3) * 72 + (p & 7);
    float mx = -1e30f;
    for (int f = sub; f <= g; f += 4)
#pragma unroll
      for (int k_ = 0; k_ < 8; ++k_)
        mx = fmaxf(mx, (float)Ls[f * 584 + base + k_ * 8]);
    mx = fmaxf(mx, __shfl_xor(mx, 1, 64));
    mx = fmaxf(mx, __shfl_xor(mx, 2, 64));
    float se = 0.f;
    for (int f = sub; f <= g; f += 4)
#pragma unroll
      for (int k_ = 0; k_ < 8; ++k_)
        se += __expf((float)Ls[f * 584 + base + k_ * 8] - mx);
    se += __shfl_xor(se, 1, 64);
    se += __shfl_xor(se, 2, 64);
    if (sub == 0) { stt[p * 2] = mx; stt[p * 2 + 1] = 1.f / se; }
  }
  __syncthreads();
  {
    const int r = t & 63, fq = t >> 6;
    const int j = r >> 3, k_ = r & 7;
    float mx[8], inv[8];
#pragma unroll
    for (int i = 0; i < 8; ++i) {
      mx[i] = stt[(j * 8 + i) * 2];
      inv[i] = stt[(j * 8 + i) * 2 + 1];
    }
    for (int fb = fq; fb <= g; fb += 4) {
      half8 row8 = *(const half8*)&Ls[fb * 584 + j * 72 + k_ * 8];
      float pr[8];
#pragma unroll
      for (int i = 0; i < 8; ++i) pr[i] = __expf((float)row8[i] - mx[i]) * inv[i];
      half8 st8;
      st8[0] = (f16)pr[0]; st8[1] = (f16)pr[2]; st8[2] = (f16)pr[4]; st8[3] = (f16)pr[6];
      st8[4] = (f16)pr[1]; st8[5] = (f16)pr[3]; st8[6] = (f16)pr[5]; st8[7] = (f16)pr[7];
      *(half8*)&Pg[sb + (int64_t)fb * 512 + r * 8] = st8;
    }
  }
}

// ---------------- K6: output — g-paired, f16 probs, 6 loads/iter, no exp ----
__global__ __launch_bounds__(512) void k_out(
    const f16* __restrict__ Pg, const f16* __restrict__ Rg,
    const f16* __restrict__ vth, float* __restrict__ out) {
  __shared__ float red[64 * 64];   // 16 KB
  const int t = threadIdx.x;
  const int wave = t >> 6, lane = t & 63, quad = lane >> 4, ln = lane & 15;
  const int fg = wave >> 2, dw = wave & 3;
  const int bh = blockIdx.x >> 4, G = blockIdx.x & 15;
  const int jl = ln & 7, ih = ln >> 3;
  const f16* vb = vth + ((int64_t)bh * 32 * 64 + dw * 16 + ln) * 64;

#pragma unroll 1
  for (int ph = 0; ph < 2; ++ph) {
    const int g = ph ? G : 31 - G;
    const int64_t sbase = ((int64_t)bh * 528 + ((g * (g + 1)) >> 1)) * 512;
    const f16* Pp = Pg + sbase;
    const f16* Rp = Rg + sbase;
    f32x4 oacc[4];
#pragma unroll
    for (int mt = 0; mt < 4; ++mt) { f32x4 z = {0.f, 0.f, 0.f, 0.f}; oacc[mt] = z; }

    half8 vA0, vA1, rA0, rA1; half4v pA0, pA1;
    half8 vB0, vB1, rB0, rB1; half4v pB0, pB1;
    auto loadit = [&](int f, half8& v0, half8& v1, half8& r0, half8& r1,
                      half4v& p0, half4v& p1) {
      const f16* Pf = Pp + f * 512;
      const f16* Rf = Rp + f * 512;
      const f16* vf = vb + (int64_t)f * 64 * 64;
      v0 = *(const half8*)&vf[quad * 8];
      v1 = *(const half8*)&vf[32 + quad * 8];
      r0 = *(const half8*)&Rf[quad * 64 + jl * 8];
      r1 = *(const half8*)&Rf[(4 + quad) * 64 + jl * 8];
      p0 = *(const half4v*)&Pf[jl * 64 + quad * 8 + ih * 4];
      p1 = *(const half4v*)&Pf[jl * 64 + (4 + quad) * 8 + ih * 4];
    };
    auto compit = [&](half8& v0, half8& v1, half8& r0, half8& r1,
                      half4v& p0, half4v& p1) {
#pragma unroll
      for (int mt = 0; mt < 4; ++mt) {
        const f16 Lh0 = p0[mt], Lh1 = p1[mt];
        half8 w0, w1;
#pragma unroll
        for (int l = 0; l < 8; ++l) { w0[l] = r0[l] * Lh0; w1[l] = r1[l] * Lh1; }
        oacc[mt] = mfma16(w0, v0, oacc[mt]);
        oacc[mt] = mfma16(w1, v1, oacc[mt]);
      }
    };
    int f = fg;
    if (f <= g) {
      loadit(f, vA0, vA1, rA0, rA1, pA0, pA1);
      while (true) {
        if (f + 2 <= g) {
          loadit(f + 2, vB0, vB1, rB0, rB1, pB0, pB1);
          compit(vA0, vA1, rA0, rA1, pA0, pA1);
          f += 2;
        } else { compit(vA0, vA1, rA0, rA1, pA0, pA1); break; }
        if (f + 2 <= g) {
          loadit(f + 2, vA0, vA1, rA0, rA1, pA0, pA1);
          compit(vB0, vB1, rB0, rB1, pB0, pB1);
          f += 2;
        } else { compit(vB0, vB1, rB0, rB1, pB0, pB1); break; }
      }
    }
    __syncthreads();
    if (fg == 1) {
#pragma unroll
      for (int mt = 0; mt < 4; ++mt)
#pragma unroll
        for (int r2 = 0; r2 < 4; ++r2)
          red[(dw * 16 + mt * 4 + r2) * 64 + lane] = oacc[mt][r2];
    }
    __syncthreads();
    if (fg == 0) {
#pragma unroll
      for (int mt = 0; mt < 4; ++mt)
#pragma unroll
        for (int r2 = 0; r2 < 4; ++r2)
          oacc[mt][r2] += red[(dw * 16 + mt * 4 + r2) * 64 + lane];
      float* ob = out + (int64_t)((bh >> 4) * 2048 + g * 64) * 1024 + (bh & 15) * 64;
#pragma unroll
      for (int mt = 0; mt < 4; ++mt)
#pragma unroll
        for (int r2 = 0; r2 < 4; ++r2)
          ob[(int64_t)(mt * 16 + quad * 4 + r2) * 1024 + dw * 16 + ln] = oacc[mt][r2];
    }
  }
}

// ---------------------------------------------------------------------------
extern "C" void kernel_launch(void* const* d_in, const int* in_sizes, int n_in,
                              void* d_out, int out_size, void* d_ws, size_t ws_size,
                              hipStream_t stream) {
  const float* x    = (const float*)d_in[0];
  const float* cosg = (const float*)d_in[1];
  const float* sing = (const float*)d_in[2];
  const float* wq   = (const float*)d_in[3];
  const float* wk   = (const float*)d_in[4];
  const float* wv   = (const float*)d_in[5];
  const float* gq   = (const float*)d_in[6];
  const float* gk   = (const float*)d_in[7];
  float* out = (float*)d_out;

  char* ws = (char*)d_ws;
  f16*   xh   = (f16*)(ws);                     // 8,388,608 B
  f16*   wcat = (f16*)(ws + 8388608);           // 6,291,456 B
  float* P    = (float*)(ws + 14680064);        // 50,331,648 B (dead after K3)
  f16*   Rg   = (f16*)(ws + 14680064);          // 17,301,504 B (aliases P)
  f16*   Pg   = (f16*)(ws + 31981568);          // 17,301,504 B (aliases P)
  f16*   qh   = (f16*)(ws + 65011712);          // 8,388,608 B
  f16*   kh   = (f16*)(ws + 73400320);          // 8,388,608 B
  f16*   vth  = (f16*)(ws + 81788928);          // 8,388,608 B
  f16*   Lg   = (f16*)(ws + 90177536);          // 17,301,504 B -> end ~108 MB

  hipLaunchKernelGGL(k_cast, dim3(1024), dim3(256), 0, stream, x, wq, wk, wv, xh, wcat);
  hipLaunchKernelGGL(k_gemm, dim3(768), dim3(256), 0, stream, xh, wcat, P);
  hipLaunchKernelGGL(k_epilogue, dim3(1024), dim3(256), 0, stream,
                     P, cosg, sing, gq, gk, qh, kh, vth);
  hipLaunchKernelGGL(k_phase, dim3(4224), dim3(256), 0, stream, qh, kh, Lg, Rg, Pg, 0);
  hipLaunchKernelGGL(k_probs, dim3(1024), dim3(256), 0, stream, Lg, Pg);
  hipLaunchKernelGGL(k_phase, dim3(4224), dim3(256), 0, stream, qh, kh, Lg, Rg, Pg, 1);
  hipLaunchKernelGGL(k_probs, dim3(1024), dim3(256), 0, stream, Lg, Pg);
  hipLaunchKernelGGL(k_out, dim3(512), dim3(512), 0, stream, Pg, Rg, vth, out);
}